// Round 8
// baseline (5222.606 us; speedup 1.0000x reference)
//
#include <hip/hip_runtime.h>
#include <hip/hip_cooperative_groups.h>
#include <hip/hip_bf16.h>
#include <stdint.h>

namespace cg = cooperative_groups;

#define NB 8
#define NS 256
#define NH 512
#define NG 1024
#define NV 256
#define NL 24
#define NC 320
#define NT 2048
#define EPSF 1e-5f

typedef __bf16 bf16;
typedef bf16 bf16x8 __attribute__((ext_vector_type(8)));
typedef float f32x4 __attribute__((ext_vector_type(4)));

__device__ __forceinline__ bf16 f2bf(float f) {
    uint32_t u = __builtin_bit_cast(uint32_t, f);
    u += 0x7FFFu + ((u >> 16) & 1u);
    uint16_t b = (uint16_t)(u >> 16);
    return __builtin_bit_cast(bf16, b);
}

__device__ __forceinline__ void gload16(const void* g, void* l) {
    __builtin_amdgcn_global_load_lds(
        (const __attribute__((address_space(1))) void*)g,
        (__attribute__((address_space(3))) void*)l,
        16, 0, 0);
}

// stage 64-row x 64-elem bf16 tile; LDS chunk XOR-swizzled via pre-swizzled src
__device__ __forceinline__ void stage64(
    const bf16* __restrict__ src, int ldk, bf16* lds, int wv_, int lane)
{
    #pragma unroll
    for (int j = 0; j < 2; ++j) {
        const int gI = wv_*2 + j;
        const int r  = gI*8 + (lane >> 3);
        const int ch = (lane & 7) ^ (lane >> 3);
        gload16(src + (size_t)r*ldk + ch*8, lds + gI*512);
    }
}
__device__ __forceinline__ const bf16x8* fragp(const bf16* lds, int row, int ch) {
    return (const bf16x8*)(lds + row*64 + ((ch ^ (row & 7)) << 3));
}

#define MFMA(a,b,c) __builtin_amdgcn_mfma_f32_16x16x32_bf16(a, b, c, 0, 0, 0)

// SMEM carve: 3 staging buffers of 16384B; epilogue Cs/Gs/Ls alias offset 0
#define SM_BYTES 49152

// ---------------- init kernels ----------------
__global__ __launch_bounds__(256) void k_cvt(
    const float* __restrict__ src, bf16* __restrict__ dst, int n8)
{
    int i = blockIdx.x*256 + threadIdx.x;
    const int stride = gridDim.x*256;
    for (; i < n8; i += stride) {
        const float* s = src + (size_t)i*8;
        bf16x8 t;
        #pragma unroll
        for (int j = 0; j < 8; ++j) t[j] = f2bf(s[j]);
        *(bf16x8*)&dst[(size_t)i*8] = t;
    }
}

__global__ __launch_bounds__(256) void k_trx(
    const float* __restrict__ x, bf16* __restrict__ xT)
{
    __shared__ bf16 Ls[64*72];
    const int s0 = blockIdx.x*64, c0 = blockIdx.y*64, b = blockIdx.z;
    const int tid = threadIdx.x;
    #pragma unroll
    for (int e = 0; e < 16; ++e) {
        int idx = tid + e*256;
        int c = idx >> 6, s = idx & 63;
        Ls[s*72 + c] = f2bf(x[(size_t)(b*NC + c0 + c)*NS + s0 + s]);
    }
    __syncthreads();
    #pragma unroll
    for (int e = 0; e < 2; ++e) {
        int idx = tid + e*256;
        int s = idx >> 3, ch = idx & 7;
        *(bf16x8*)&xT[(size_t)(b*NS + s0 + s)*NC + c0 + ch*8] =
            *(const bf16x8*)&Ls[s*72 + ch*8];
    }
}

// ---------------- phase bodies (shared by coop kernel and fallback wrappers) --
struct Params {
    const float *rms_local, *rms_global, *rms_ffn, *head_rms;
    const float *alpha_local, *alpha_global, *alpha_mlp, *head_scale;
    const float *w_local, *w_global;
    float *h, *ss, *out;
    const bf16 *xT, *stem_wb, *head_wb, *wv_b, *wg_b, *wo_b;
    bf16 *g, *a_bf;
};

__device__ void d_stem(const Params& P, char* sm, int u) {
    bf16* As = (bf16*)sm;             // [2][4096] bf16 = 16384B
    bf16* Bs = (bf16*)(sm + 16384);
    float* Cs = (float*)sm;           // epilogue alias (16896B)
    const int t0 = (u >> 3)*64, n0 = (u & 7)*64;
    const int tid = threadIdx.x, lane = tid & 63, wv_ = tid >> 6;
    const int wm = wv_ >> 1, wn = wv_ & 1;
    const int fr = lane & 15, kq = lane >> 4;
    const bf16* Ag = P.xT + (size_t)t0*NC;
    const bf16* Bg = P.stem_wb + (size_t)n0*NC;
    f32x4 acc[2][2] = {};
    stage64(Ag, NC, As, wv_, lane);
    stage64(Bg, NC, Bs, wv_, lane);
    __syncthreads();
    const int NIT = NC/64;
    for (int it = 0; it < NIT; ++it) {
        const int cur = it & 1;
        if (it + 1 < NIT) {
            stage64(Ag + (it+1)*64, NC, As + (cur^1)*4096, wv_, lane);
            stage64(Bg + (it+1)*64, NC, Bs + (cur^1)*4096, wv_, lane);
        }
        #pragma unroll
        for (int kk = 0; kk < 2; ++kk) {
            const int ch = kk*4 + kq;
            bf16x8 a0 = *fragp(As + cur*4096, wm*32 + fr,      ch);
            bf16x8 a1 = *fragp(As + cur*4096, wm*32 + 16 + fr, ch);
            bf16x8 b0 = *fragp(Bs + cur*4096, wn*32 + fr,      ch);
            bf16x8 b1 = *fragp(Bs + cur*4096, wn*32 + 16 + fr, ch);
            acc[0][0] = MFMA(a0, b0, acc[0][0]);
            acc[0][1] = MFMA(a0, b1, acc[0][1]);
            acc[1][0] = MFMA(a1, b0, acc[1][0]);
            acc[1][1] = MFMA(a1, b1, acc[1][1]);
        }
        __syncthreads();
    }
    const int row4 = (lane >> 4)*4, col = lane & 15;
    #pragma unroll
    for (int mi = 0; mi < 2; ++mi)
      #pragma unroll
      for (int ni = 0; ni < 2; ++ni)
        #pragma unroll
        for (int r = 0; r < 4; ++r)
            Cs[(wm*32 + mi*16 + row4 + r)*66 + wn*32 + ni*16 + col] = acc[mi][ni][r];
    __syncthreads();
    const int rr = tid >> 2, c16 = (tid & 3)*16;
    float ssum = 0.f;
    float* dst = &P.h[(size_t)(t0 + rr)*NH + n0 + c16];
    #pragma unroll
    for (int i = 0; i < 16; ++i) {
        float v = Cs[rr*66 + c16 + i];
        dst[i] = v;
        ssum += v*v;
    }
    ssum += __shfl_xor(ssum, 1, 64);
    ssum += __shfl_xor(ssum, 2, 64);
    if ((tid & 3) == 0) atomicAdd(&P.ss[t0 + rr], ssum);
    __syncthreads();
}

template<int STR>
__device__ void d_mix(
    float* __restrict__ h, const float* __restrict__ ss_in,
    const float* __restrict__ w, const float* __restrict__ rmsw,
    const float* __restrict__ alpha_p, float* __restrict__ ss_out,
    char* sm, int u)
{
    float* raw = (float*)sm;             // 4096B
    float* rstdL = (float*)(sm + 4096);  // 64B
    const int bx = u >> 3, c0 = (u & 7)*64;
    const int b = bx >> 4, g = bx & 15;
    const int tid = threadIdx.x;
    const int c = tid & 63, pq = tid >> 6;
    const int base = b*NS + (STR == 1 ? g*16 : g);
    if (tid < 16) rstdL[tid] = rsqrtf(ss_in[base + tid*STR]*(1.f/NH) + EPSF);
    #pragma unroll
    for (int e = 0; e < 4; ++e) {
        int idx = tid + e*256;
        int j = idx >> 6, cc = idx & 63;
        raw[j*64 + cc] = h[(size_t)(base + j*STR)*NH + c0 + cc];
    }
    __syncthreads();
    float ureg[16];
    #pragma unroll
    for (int j = 0; j < 16; ++j) ureg[j] = raw[j*64 + c] * rstdL[j];
    const float al = *alpha_p;
    const float rc = rmsw[c0 + c] * al;
    const float* wrow = &w[(size_t)(c0 + c)*256 + pq*64];
    float hn[4];
    #pragma unroll
    for (int q = 0; q < 4; ++q) {
        float acc = 0.f;
        #pragma unroll
        for (int jv = 0; jv < 4; ++jv) {
            float4 w4 = *(const float4*)&wrow[q*16 + jv*4];
            acc += w4.x*ureg[jv*4+0] + w4.y*ureg[jv*4+1] + w4.z*ureg[jv*4+2] + w4.w*ureg[jv*4+3];
        }
        const int p = pq*4 + q;
        hn[q] = raw[p*64 + c] + rc*acc;
        h[(size_t)(base + p*STR)*NH + c0 + c] = hn[q];
    }
    #pragma unroll
    for (int q = 0; q < 4; ++q) {
        float ssum = hn[q]*hn[q];
        ssum += __shfl_xor(ssum, 1, 64);
        ssum += __shfl_xor(ssum, 2, 64);
        ssum += __shfl_xor(ssum, 4, 64);
        ssum += __shfl_xor(ssum, 8, 64);
        ssum += __shfl_xor(ssum, 16, 64);
        ssum += __shfl_xor(ssum, 32, 64);
        if (c == 0) atomicAdd(&ss_out[base + (pq*4 + q)*STR], ssum);
    }
    __syncthreads();
}

__device__ void d_norm(
    const float* __restrict__ h, const float* __restrict__ ss_in,
    const float* __restrict__ rmsw, bf16* __restrict__ a, int u)
{
    const int t = u*4 + (threadIdx.x >> 6);
    const int c8 = (threadIdx.x & 63)*8;
    const float rstd = rsqrtf(ss_in[t]*(1.f/NH) + EPSF);
    const float* src = &h[(size_t)t*NH + c8];
    float4 h0 = *(const float4*)&src[0];
    float4 h1 = *(const float4*)&src[4];
    float4 w0 = *(const float4*)&rmsw[c8];
    float4 w1 = *(const float4*)&rmsw[c8 + 4];
    bf16x8 o;
    o[0] = f2bf(h0.x*rstd*w0.x); o[1] = f2bf(h0.y*rstd*w0.y);
    o[2] = f2bf(h0.z*rstd*w0.z); o[3] = f2bf(h0.w*rstd*w0.w);
    o[4] = f2bf(h1.x*rstd*w1.x); o[5] = f2bf(h1.y*rstd*w1.y);
    o[6] = f2bf(h1.z*rstd*w1.z); o[7] = f2bf(h1.w*rstd*w1.w);
    *(bf16x8*)&a[(size_t)t*NH + c8] = o;
}

__device__ void d_mlp_in(
    const bf16* __restrict__ a, const bf16* __restrict__ wvl,
    const bf16* __restrict__ wgl, bf16* __restrict__ g, char* sm, int u)
{
    bf16* As  = (bf16*)sm;
    bf16* B1s = (bf16*)(sm + 16384);
    bf16* B3s = (bf16*)(sm + 32768);
    bf16* Gs  = (bf16*)sm;            // epilogue alias (9216B)
    const int t0 = (u >> 4)*64, n0 = (u & 15)*64;
    const int tid = threadIdx.x, lane = tid & 63, wv_ = tid >> 6;
    const int wm = wv_ >> 1, wn = wv_ & 1;
    const int fr = lane & 15, kq = lane >> 4;
    const bf16* Ag = a   + (size_t)t0*NH;
    const bf16* Vg = wvl + (size_t)n0*NH;
    const bf16* Gg = wgl + (size_t)n0*NH;
    f32x4 acc1[2][2] = {}, acc3[2][2] = {};
    stage64(Ag, NH, As,  wv_, lane);
    stage64(Vg, NH, B1s, wv_, lane);
    stage64(Gg, NH, B3s, wv_, lane);
    __syncthreads();
    const int NIT = NH/64;
    for (int it = 0; it < NIT; ++it) {
        const int cur = it & 1;
        if (it + 1 < NIT) {
            stage64(Ag + (it+1)*64, NH, As  + (cur^1)*4096, wv_, lane);
            stage64(Vg + (it+1)*64, NH, B1s + (cur^1)*4096, wv_, lane);
            stage64(Gg + (it+1)*64, NH, B3s + (cur^1)*4096, wv_, lane);
        }
        #pragma unroll
        for (int kk = 0; kk < 2; ++kk) {
            const int ch = kk*4 + kq;
            bf16x8 a0 = *fragp(As  + cur*4096, wm*32 + fr,      ch);
            bf16x8 a1 = *fragp(As  + cur*4096, wm*32 + 16 + fr, ch);
            bf16x8 u0 = *fragp(B1s + cur*4096, wn*32 + fr,      ch);
            bf16x8 u1 = *fragp(B1s + cur*4096, wn*32 + 16 + fr, ch);
            bf16x8 v0 = *fragp(B3s + cur*4096, wn*32 + fr,      ch);
            bf16x8 v1 = *fragp(B3s + cur*4096, wn*32 + 16 + fr, ch);
            acc1[0][0] = MFMA(a0, u0, acc1[0][0]);
            acc1[0][1] = MFMA(a0, u1, acc1[0][1]);
            acc1[1][0] = MFMA(a1, u0, acc1[1][0]);
            acc1[1][1] = MFMA(a1, u1, acc1[1][1]);
            acc3[0][0] = MFMA(a0, v0, acc3[0][0]);
            acc3[0][1] = MFMA(a0, v1, acc3[0][1]);
            acc3[1][0] = MFMA(a1, v0, acc3[1][0]);
            acc3[1][1] = MFMA(a1, v1, acc3[1][1]);
        }
        __syncthreads();
    }
    const int row4 = (lane >> 4)*4, col = lane & 15;
    #pragma unroll
    for (int mi = 0; mi < 2; ++mi)
      #pragma unroll
      for (int ni = 0; ni < 2; ++ni)
        #pragma unroll
        for (int r = 0; r < 4; ++r) {
            float xv = acc1[mi][ni][r];
            float gl = (xv / (1.f + __expf(-xv))) * acc3[mi][ni][r];
            Gs[(wm*32 + mi*16 + row4 + r)*72 + wn*32 + ni*16 + col] = f2bf(gl);
        }
    __syncthreads();
    const int rr = tid >> 2, c16 = (tid & 3)*16;
    bf16x8 o0 = *(const bf16x8*)&Gs[rr*72 + c16];
    bf16x8 o1 = *(const bf16x8*)&Gs[rr*72 + c16 + 8];
    *(bf16x8*)&g[(size_t)(t0 + rr)*NG + n0 + c16] = o0;
    *(bf16x8*)&g[(size_t)(t0 + rr)*NG + n0 + c16 + 8] = o1;
    __syncthreads();
}

__device__ void d_mlp_out(
    const bf16* __restrict__ g, const bf16* __restrict__ wol,
    const float* __restrict__ alpha_p, float* __restrict__ h,
    float* __restrict__ ss_out, char* sm, int u)
{
    bf16* As = (bf16*)sm;
    bf16* Bs = (bf16*)(sm + 16384);
    float* Cs = (float*)sm;           // epilogue alias
    const int t0 = (u >> 3)*64, n0 = (u & 7)*64;
    const int tid = threadIdx.x, lane = tid & 63, wv_ = tid >> 6;
    const int wm = wv_ >> 1, wn = wv_ & 1;
    const int fr = lane & 15, kq = lane >> 4;
    const bf16* Ag = g   + (size_t)t0*NG;
    const bf16* Bg = wol + (size_t)n0*NG;
    f32x4 acc[2][2] = {};
    stage64(Ag, NG, As, wv_, lane);
    stage64(Bg, NG, Bs, wv_, lane);
    __syncthreads();
    const int NIT = NG/64;
    for (int it = 0; it < NIT; ++it) {
        const int cur = it & 1;
        if (it + 1 < NIT) {
            stage64(Ag + (it+1)*64, NG, As + (cur^1)*4096, wv_, lane);
            stage64(Bg + (it+1)*64, NG, Bs + (cur^1)*4096, wv_, lane);
        }
        #pragma unroll
        for (int kk = 0; kk < 2; ++kk) {
            const int ch = kk*4 + kq;
            bf16x8 a0 = *fragp(As + cur*4096, wm*32 + fr,      ch);
            bf16x8 a1 = *fragp(As + cur*4096, wm*32 + 16 + fr, ch);
            bf16x8 b0 = *fragp(Bs + cur*4096, wn*32 + fr,      ch);
            bf16x8 b1 = *fragp(Bs + cur*4096, wn*32 + 16 + fr, ch);
            acc[0][0] = MFMA(a0, b0, acc[0][0]);
            acc[0][1] = MFMA(a0, b1, acc[0][1]);
            acc[1][0] = MFMA(a1, b0, acc[1][0]);
            acc[1][1] = MFMA(a1, b1, acc[1][1]);
        }
        __syncthreads();
    }
    const int row4 = (lane >> 4)*4, col = lane & 15;
    #pragma unroll
    for (int mi = 0; mi < 2; ++mi)
      #pragma unroll
      for (int ni = 0; ni < 2; ++ni)
        #pragma unroll
        for (int r = 0; r < 4; ++r)
            Cs[(wm*32 + mi*16 + row4 + r)*66 + wn*32 + ni*16 + col] = acc[mi][ni][r];
    __syncthreads();
    const float am = *alpha_p;
    const int rr = tid >> 2, c16 = (tid & 3)*16;
    float* dst = &h[(size_t)(t0 + rr)*NH + n0 + c16];
    float ssum = 0.f;
    #pragma unroll
    for (int i = 0; i < 16; ++i) {
        float hn = dst[i] + am * Cs[rr*66 + c16 + i];
        dst[i] = hn;
        ssum += hn*hn;
    }
    ssum += __shfl_xor(ssum, 1, 64);
    ssum += __shfl_xor(ssum, 2, 64);
    if ((tid & 3) == 0) atomicAdd(&ss_out[t0 + rr], ssum);
    __syncthreads();
}

__device__ void d_head(
    const bf16* __restrict__ a, const bf16* __restrict__ hw,
    const float* __restrict__ scale_p, float* __restrict__ out,
    char* sm, int u)
{
    bf16* As = (bf16*)sm;
    bf16* Bs = (bf16*)(sm + 16384);
    float* Ls = (float*)sm;           // epilogue alias
    const int t0 = (u >> 2)*64, n0 = (u & 3)*64;
    const int tid = threadIdx.x, lane = tid & 63, wv_ = tid >> 6;
    const int wm = wv_ >> 1, wn = wv_ & 1;
    const int fr = lane & 15, kq = lane >> 4;
    const bf16* Ag = a  + (size_t)t0*NH;
    const bf16* Bg = hw + (size_t)n0*NH;
    f32x4 acc[2][2] = {};
    stage64(Ag, NH, As, wv_, lane);
    stage64(Bg, NH, Bs, wv_, lane);
    __syncthreads();
    const int NIT = NH/64;
    for (int it = 0; it < NIT; ++it) {
        const int cur = it & 1;
        if (it + 1 < NIT) {
            stage64(Ag + (it+1)*64, NH, As + (cur^1)*4096, wv_, lane);
            stage64(Bg + (it+1)*64, NH, Bs + (cur^1)*4096, wv_, lane);
        }
        #pragma unroll
        for (int kk = 0; kk < 2; ++kk) {
            const int ch = kk*4 + kq;
            bf16x8 a0 = *fragp(As + cur*4096, wm*32 + fr,      ch);
            bf16x8 a1 = *fragp(As + cur*4096, wm*32 + 16 + fr, ch);
            bf16x8 b0 = *fragp(Bs + cur*4096, wn*32 + fr,      ch);
            bf16x8 b1 = *fragp(Bs + cur*4096, wn*32 + 16 + fr, ch);
            acc[0][0] = MFMA(a0, b0, acc[0][0]);
            acc[0][1] = MFMA(a0, b1, acc[0][1]);
            acc[1][0] = MFMA(a1, b0, acc[1][0]);
            acc[1][1] = MFMA(a1, b1, acc[1][1]);
        }
        __syncthreads();
    }
    const float sc = *scale_p;
    const int row4 = (lane >> 4)*4, col = lane & 15;
    #pragma unroll
    for (int mi = 0; mi < 2; ++mi)
      #pragma unroll
      for (int ni = 0; ni < 2; ++ni)
        #pragma unroll
        for (int r = 0; r < 4; ++r)
            Ls[(wm*32 + mi*16 + row4 + r)*66 + wn*32 + ni*16 + col] = sc * acc[mi][ni][r];
    __syncthreads();
    const int vv = tid >> 2, s16 = (tid & 3)*16;
    const int b = t0 >> 8, s0 = t0 & 255;
    float* dst = &out[((size_t)(b*NV + n0 + vv))*NS + s0 + s16];
    #pragma unroll
    for (int i = 0; i < 16; ++i) dst[i] = Ls[(s16 + i)*66 + vv];
    __syncthreads();
}

// ---------------- cooperative whole-network kernel ----------------
__global__ __launch_bounds__(256) void k_net(Params P) {
    cg::grid_group grid = cg::this_grid();
    __shared__ __align__(16) char sm[SM_BYTES];
    const int nb = gridDim.x, bid = blockIdx.x;

    for (int u = bid; u < 256; u += nb) d_stem(P, sm, u);
    grid.sync();

    for (int l = 0; l < NL; ++l) {
        float* ssl = P.ss + l*NT;
        float* ssg = P.ss + 24*NT + l*NT;
        float* ssf = P.ss + 48*NT + l*NT;
        float* ssn = (l == NL-1) ? (P.ss + 72*NT) : (P.ss + (l+1)*NT);

        for (int u = bid; u < 1024; u += nb)
            d_mix<1>(P.h, ssl, P.w_local + (size_t)l*NH*256,
                     P.rms_local + l*NH, P.alpha_local + l, ssg, sm, u);
        grid.sync();
        for (int u = bid; u < 1024; u += nb)
            d_mix<16>(P.h, ssg, P.w_global + (size_t)l*NH*256,
                      P.rms_global + l*NH, P.alpha_global + l, ssf, sm, u);
        grid.sync();
        for (int u = bid; u < 512; u += nb)
            d_norm(P.h, ssf, P.rms_ffn + l*NH, P.a_bf, u);
        grid.sync();
        for (int u = bid; u < 512; u += nb)
            d_mlp_in(P.a_bf, P.wv_b + (size_t)l*NG*NH,
                     P.wg_b + (size_t)l*NG*NH, P.g, sm, u);
        grid.sync();
        for (int u = bid; u < 256; u += nb)
            d_mlp_out(P.g, P.wo_b + (size_t)l*NH*NG, P.alpha_mlp + l,
                      P.h, ssn, sm, u);
        grid.sync();
    }

    for (int u = bid; u < 512; u += nb)
        d_norm(P.h, P.ss + 72*NT, P.head_rms, P.a_bf, u);
    grid.sync();
    for (int u = bid; u < 128; u += nb)
        d_head(P.a_bf, P.head_wb, P.head_scale, P.out, sm, u);
}

// ---------------- fallback wrappers (round-4 style multi-launch) ----------------
__global__ __launch_bounds__(256) void g_stem(Params P) {
    __shared__ __align__(16) char sm[SM_BYTES];
    d_stem(P, sm, blockIdx.x);
}
template<int STR>
__global__ __launch_bounds__(256) void g_mix(
    float* h, const float* ss_in, const float* w, const float* rmsw,
    const float* alpha_p, float* ss_out)
{
    __shared__ __align__(16) char sm[8192];
    d_mix<STR>(h, ss_in, w, rmsw, alpha_p, ss_out, sm, blockIdx.x);
}
__global__ __launch_bounds__(256) void g_norm(
    const float* h, const float* ss_in, const float* rmsw, bf16* a)
{
    d_norm(h, ss_in, rmsw, a, blockIdx.x);
}
__global__ __launch_bounds__(256) void g_mlp_in(
    const bf16* a, const bf16* wvl, const bf16* wgl, bf16* g)
{
    __shared__ __align__(16) char sm[SM_BYTES];
    d_mlp_in(a, wvl, wgl, g, sm, blockIdx.x);
}
__global__ __launch_bounds__(256) void g_mlp_out(
    const bf16* g, const bf16* wol, const float* alpha_p, float* h, float* ss_out)
{
    __shared__ __align__(16) char sm[SM_BYTES];
    d_mlp_out(g, wol, alpha_p, h, ss_out, sm, blockIdx.x);
}
__global__ __launch_bounds__(256) void g_head(
    const bf16* a, const bf16* hw, const float* scale_p, float* out)
{
    __shared__ __align__(16) char sm[SM_BYTES];
    d_head(a, hw, scale_p, out, sm, blockIdx.x);
}

extern "C" void kernel_launch(void* const* d_in, const int* in_sizes, int n_in,
                              void* d_out, int out_size, void* d_ws, size_t ws_size,
                              hipStream_t stream) {
    const float* x          = (const float*)d_in[0];
    const float* stem_w     = (const float*)d_in[1];
    const float* rms_local  = (const float*)d_in[2];
    const float* rms_global = (const float*)d_in[3];
    const float* rms_ffn    = (const float*)d_in[4];
    const float* alpha_local  = (const float*)d_in[5];
    const float* alpha_global = (const float*)d_in[6];
    const float* alpha_mlp    = (const float*)d_in[7];
    const float* w_local    = (const float*)d_in[8];
    const float* w_global   = (const float*)d_in[9];
    const float* wv         = (const float*)d_in[10];
    const float* wg         = (const float*)d_in[11];
    const float* wo         = (const float*)d_in[12];
    const float* head_rms   = (const float*)d_in[13];
    const float* head_scale = (const float*)d_in[14];
    const float* head_w     = (const float*)d_in[15];
    float* out = (float*)d_out;

    char* ws = (char*)d_ws;
    const size_t MB = 1024*1024;
    float* h    = (float*)(ws);
    bf16*  g    = (bf16*)(ws + 4*MB);
    bf16*  a_bf = (bf16*)(ws + 8*MB);
    float* ss   = (float*)(ws + 10*MB);
    bf16* xT      = (bf16*)(ws + 16*MB);
    bf16* stem_wb = (bf16*)(ws + 18*MB);
    bf16* head_wb = (bf16*)(ws + 19*MB);
    bf16* wv_b    = (bf16*)(ws + 20*MB);
    bf16* wg_b    = (bf16*)(ws + 44*MB);
    bf16* wo_b    = (bf16*)(ws + 68*MB);

    hipMemsetAsync(ss, 0, (size_t)73*NT*sizeof(float), stream);

    k_cvt<<<80, 256, 0, stream>>>(stem_w, stem_wb, NH*NC/8);
    k_cvt<<<64, 256, 0, stream>>>(head_w, head_wb, NV*NH/8);
    k_trx<<<dim3(4, 5, 8), 256, 0, stream>>>(x, xT);
    k_cvt<<<2048, 256, 0, stream>>>(wv, wv_b, NL*NG*NH/8);
    k_cvt<<<2048, 256, 0, stream>>>(wg, wg_b, NL*NG*NH/8);
    k_cvt<<<2048, 256, 0, stream>>>(wo, wo_b, NL*NH*NG/8);

    Params p;
    p.rms_local = rms_local; p.rms_global = rms_global; p.rms_ffn = rms_ffn;
    p.head_rms = head_rms;
    p.alpha_local = alpha_local; p.alpha_global = alpha_global;
    p.alpha_mlp = alpha_mlp; p.head_scale = head_scale;
    p.w_local = w_local; p.w_global = w_global;
    p.h = h; p.ss = ss; p.out = out;
    p.xT = xT; p.stem_wb = stem_wb; p.head_wb = head_wb;
    p.wv_b = wv_b; p.wg_b = wg_b; p.wo_b = wo_b;
    p.g = g; p.a_bf = a_bf;

    // --- cooperative launch with runtime occupancy clamp + checked fallback ---
    int maxB = 0;
    hipError_t qe = hipOccupancyMaxActiveBlocksPerMultiprocessor(
        &maxB, (const void*)k_net, 256, 0);
    hipError_t le = hipErrorUnknown;
    void* kargs[] = { &p };
    if (qe == hipSuccess && maxB >= 1) {
        int nb = maxB * 256;          // 256 CUs on MI355X
        if (nb > 512) nb = 512;
        le = hipLaunchCooperativeKernel((void*)k_net, dim3(nb), dim3(256),
                                        kargs, 0, stream);
        if (le != hipSuccess && nb != 256) {
            le = hipLaunchCooperativeKernel((void*)k_net, dim3(256), dim3(256),
                                            kargs, 0, stream);
        }
    }
    if (le != hipSuccess) {
        // fallback: verified multi-launch path
        g_stem<<<256, 256, 0, stream>>>(p);
        for (int l = 0; l < NL; ++l) {
            float* ssl = ss + l*NT;
            float* ssg = ss + 24*NT + l*NT;
            float* ssf = ss + 48*NT + l*NT;
            float* ssn = (l == NL-1) ? (ss + 72*NT) : (ss + (l+1)*NT);
            g_mix<1><<<1024, 256, 0, stream>>>(
                h, ssl, w_local + (size_t)l*NH*256,
                rms_local + l*NH, alpha_local + l, ssg);
            g_mix<16><<<1024, 256, 0, stream>>>(
                h, ssg, w_global + (size_t)l*NH*256,
                rms_global + l*NH, alpha_global + l, ssf);
            g_norm<<<512, 256, 0, stream>>>(h, ssf, rms_ffn + l*NH, a_bf);
            g_mlp_in<<<512, 256, 0, stream>>>(
                a_bf, wv_b + (size_t)l*NG*NH, wg_b + (size_t)l*NG*NH, g);
            g_mlp_out<<<256, 256, 0, stream>>>(
                g, wo_b + (size_t)l*NH*NG, alpha_mlp + l, h, ssn);
        }
        g_norm<<<512, 256, 0, stream>>>(h, ss + 72*NT, head_rms, a_bf);
        g_head<<<128, 256, 0, stream>>>(a_bf, head_wb, head_scale, out);
    }
}

// Round 9
// 1376.125 us; speedup vs baseline: 3.7952x; 3.7952x over previous
//
#include <hip/hip_runtime.h>
#include <hip/hip_bf16.h>
#include <stdint.h>

#define NB 8
#define NS 256
#define NH 512
#define NG 1024
#define NV 256
#define NL 24
#define NC 320
#define NT 2048
#define EPSF 1e-5f

typedef __bf16 bf16;
typedef bf16 bf16x8 __attribute__((ext_vector_type(8)));
typedef float f32x4 __attribute__((ext_vector_type(4)));

__device__ __forceinline__ bf16 f2bf(float f) {
    uint32_t u = __builtin_bit_cast(uint32_t, f);
    u += 0x7FFFu + ((u >> 16) & 1u);
    uint16_t b = (uint16_t)(u >> 16);
    return __builtin_bit_cast(bf16, b);
}
__device__ __forceinline__ uint16_t bfbits(float f) {
    uint32_t u = __builtin_bit_cast(uint32_t, f);
    u += 0x7FFFu + ((u >> 16) & 1u);
    return (uint16_t)(u >> 16);
}

__device__ __forceinline__ void gload16(const void* g, void* l) {
    __builtin_amdgcn_global_load_lds(
        (const __attribute__((address_space(1))) void*)g,
        (__attribute__((address_space(3))) void*)l,
        16, 0, 0);
}

// stage 64-row x 64-elem bf16 tile; LDS chunk XOR-swizzled via pre-swizzled src
__device__ __forceinline__ void stage64(
    const bf16* __restrict__ src, int ldk, bf16* lds, int wv_, int lane)
{
    #pragma unroll
    for (int j = 0; j < 2; ++j) {
        const int gI = wv_*2 + j;
        const int r  = gI*8 + (lane >> 3);
        const int ch = (lane & 7) ^ (lane >> 3);
        gload16(src + (size_t)r*ldk + ch*8, lds + gI*512);
    }
}
__device__ __forceinline__ const bf16x8* fragp(const bf16* lds, int row, int ch) {
    return (const bf16x8*)(lds + row*64 + ((ch ^ (row & 7)) << 3));
}

#define MFMA(a,b,c) __builtin_amdgcn_mfma_f32_16x16x32_bf16(a, b, c, 0, 0, 0)

// ---------------- init: convert the three big MLP weights in one dispatch
__global__ __launch_bounds__(256) void k_cvt3(
    const float* __restrict__ s0, const float* __restrict__ s1,
    const float* __restrict__ s2, bf16* __restrict__ d0,
    bf16* __restrict__ d1, bf16* __restrict__ d2, int n8)
{
    const int N = 3*n8;
    for (int i = blockIdx.x*256 + threadIdx.x; i < N; i += gridDim.x*256) {
        const float* s; bf16* d; int j;
        if (i < n8)        { s = s0; d = d0; j = i; }
        else if (i < 2*n8) { s = s1; d = d1; j = i - n8; }
        else               { s = s2; d = d2; j = i - 2*n8; }
        const float* sp = s + (size_t)j*8;
        bf16x8 t;
        #pragma unroll
        for (int e = 0; e < 8; ++e) t[e] = f2bf(sp[e]);
        *(bf16x8*)&d[(size_t)j*8] = t;
    }
}

// ---------------- init: stem + head weights
__global__ __launch_bounds__(256) void k_cvt2(
    const float* __restrict__ s0, const float* __restrict__ s1,
    bf16* __restrict__ d0, bf16* __restrict__ d1, int n8a, int n8b)
{
    const int N = n8a + n8b;
    for (int i = blockIdx.x*256 + threadIdx.x; i < N; i += gridDim.x*256) {
        const float* s; bf16* d; int j;
        if (i < n8a) { s = s0; d = d0; j = i; }
        else         { s = s1; d = d1; j = i - n8a; }
        const float* sp = s + (size_t)j*8;
        bf16x8 t;
        #pragma unroll
        for (int e = 0; e < 8; ++e) t[e] = f2bf(sp[e]);
        *(bf16x8*)&d[(size_t)j*8] = t;
    }
}

// ---------------- init: transpose mix weights [l][c][pj] f32 -> [l][pj][c] bf16
__global__ __launch_bounds__(256) void k_trw(
    const float* __restrict__ wl, const float* __restrict__ wg,
    bf16* __restrict__ wlT, bf16* __restrict__ wgT)
{
    __shared__ bf16 Ls[64*72];
    const int pj0 = blockIdx.x*64, c0 = blockIdx.y*64;
    const int z = blockIdx.z, l = z >> 1;
    const float* src = (z & 1) ? wg : wl;
    bf16* dst = (z & 1) ? wgT : wlT;
    src += (size_t)l*NH*256;
    dst += (size_t)l*256*NH;
    const int tid = threadIdx.x;
    #pragma unroll
    for (int e = 0; e < 16; ++e) {
        int idx = e*256 + tid;
        int cl = idx >> 6, pj = idx & 63;
        Ls[pj*72 + cl] = f2bf(src[(size_t)(c0 + cl)*256 + pj0 + pj]);
    }
    __syncthreads();
    #pragma unroll
    for (int e = 0; e < 2; ++e) {
        int idx = e*256 + tid;
        int row = idx >> 3, ch8 = idx & 7;
        *(bf16x8*)&dst[(size_t)(pj0 + row)*NH + c0 + ch8*8] =
            *(const bf16x8*)&Ls[row*72 + ch8*8];
    }
}

// ---------------- init: x[b][c][s] f32 -> xT[b*256+s][c] bf16
__global__ __launch_bounds__(256) void k_trx(
    const float* __restrict__ x, bf16* __restrict__ xT)
{
    __shared__ bf16 Ls[64*72];
    const int s0 = blockIdx.x*64, c0 = blockIdx.y*64, b = blockIdx.z;
    const int tid = threadIdx.x;
    #pragma unroll
    for (int e = 0; e < 16; ++e) {
        int idx = tid + e*256;
        int c = idx >> 6, s = idx & 63;
        Ls[s*72 + c] = f2bf(x[(size_t)(b*NC + c0 + c)*NS + s0 + s]);
    }
    __syncthreads();
    #pragma unroll
    for (int e = 0; e < 2; ++e) {
        int idx = tid + e*256;
        int s = idx >> 3, ch = idx & 7;
        *(bf16x8*)&xT[(size_t)(b*NS + s0 + s)*NC + c0 + ch*8] =
            *(const bf16x8*)&Ls[s*72 + ch*8];
    }
}

// ---------------- stem GEMM: h[t,o] = xT[t,:] . wb[o,:]
__global__ __launch_bounds__(256) void k_stem_b(
    const bf16* __restrict__ xT, const bf16* __restrict__ wb,
    float* __restrict__ h)
{
    __shared__ __align__(16) bf16 As[2][4096], Bs[2][4096];
    __shared__ float Cs[64*66];
    const int t0 = blockIdx.x*64, n0 = blockIdx.y*64;
    const int tid = threadIdx.x, lane = tid & 63, wv_ = tid >> 6;
    const int wm = wv_ >> 1, wn = wv_ & 1;
    const int fr = lane & 15, kq = lane >> 4;
    const bf16* Ag = xT + (size_t)t0*NC;
    const bf16* Bg = wb + (size_t)n0*NC;
    f32x4 acc[2][2] = {};
    stage64(Ag, NC, As[0], wv_, lane);
    stage64(Bg, NC, Bs[0], wv_, lane);
    __syncthreads();
    const int NIT = NC/64;
    for (int it = 0; it < NIT; ++it) {
        const int cur = it & 1;
        if (it + 1 < NIT) {
            stage64(Ag + (it+1)*64, NC, As[cur^1], wv_, lane);
            stage64(Bg + (it+1)*64, NC, Bs[cur^1], wv_, lane);
        }
        #pragma unroll
        for (int kk = 0; kk < 2; ++kk) {
            const int ch = kk*4 + kq;
            bf16x8 a0 = *fragp(As[cur], wm*32 + fr,      ch);
            bf16x8 a1 = *fragp(As[cur], wm*32 + 16 + fr, ch);
            bf16x8 b0 = *fragp(Bs[cur], wn*32 + fr,      ch);
            bf16x8 b1 = *fragp(Bs[cur], wn*32 + 16 + fr, ch);
            acc[0][0] = MFMA(a0, b0, acc[0][0]);
            acc[0][1] = MFMA(a0, b1, acc[0][1]);
            acc[1][0] = MFMA(a1, b0, acc[1][0]);
            acc[1][1] = MFMA(a1, b1, acc[1][1]);
        }
        __syncthreads();
    }
    const int row4 = (lane >> 4)*4, col = lane & 15;
    #pragma unroll
    for (int mi = 0; mi < 2; ++mi)
      #pragma unroll
      for (int ni = 0; ni < 2; ++ni)
        #pragma unroll
        for (int r = 0; r < 4; ++r)
            Cs[(wm*32 + mi*16 + row4 + r)*66 + wn*32 + ni*16 + col] = acc[mi][ni][r];
    __syncthreads();
    const int rr = tid >> 2, c16 = (tid & 3)*16;
    float* dst = &h[(size_t)(t0 + rr)*NH + n0 + c16];
    #pragma unroll
    for (int i = 0; i < 16; ++i) dst[i] = Cs[rr*66 + c16 + i];
}

// ---------------- unified mix with block-local RMS norm
// STR=1 (local): tokens base+k, base = b*256 + gi*16
// STR=16(global): tokens base+16k, base = b*256 + gi
// FFN: additionally compute ffn-norm of updated rows and write a_bf
template<int STR, bool FFN>
__global__ __launch_bounds__(256) void k_mix2(
    float* __restrict__ h, const bf16* __restrict__ wT,
    const float* __restrict__ rmsw, const float* __restrict__ alpha_p,
    const float* __restrict__ rmsw_ffn, bf16* __restrict__ a_bf)
{
    __shared__ float raw[16][512];
    __shared__ float red[4][16];
    __shared__ float rstdL[16];
    const int b = blockIdx.x, gi = blockIdx.y;
    const int base = b*NS + (STR == 1 ? gi*16 : gi);
    const int tid = threadIdx.x, lane = tid & 63, wid = tid >> 6;
    #pragma unroll
    for (int e = 0; e < 8; ++e) {
        int idx = e*256 + tid;
        int k = idx >> 7, c4 = idx & 127;
        *(float4*)&raw[k][c4*4] = *(const float4*)&h[(size_t)(base + k*STR)*NH + c4*4];
    }
    __syncthreads();
    const int c0 = tid*2;
    float u0[16], u1[16], part[16];
    #pragma unroll
    for (int k = 0; k < 16; ++k) {
        float A = raw[k][c0], B = raw[k][c0+1];
        u0[k] = A; u1[k] = B; part[k] = A*A + B*B;
    }
    #pragma unroll
    for (int m = 1; m < 64; m <<= 1)
        #pragma unroll
        for (int k = 0; k < 16; ++k) part[k] += __shfl_xor(part[k], m, 64);
    if (lane == 0) {
        #pragma unroll
        for (int k = 0; k < 16; ++k) red[wid][k] = part[k];
    }
    __syncthreads();
    if (tid < 16)
        rstdL[tid] = rsqrtf((red[0][tid]+red[1][tid]+red[2][tid]+red[3][tid])*(1.f/NH) + EPSF);
    __syncthreads();
    #pragma unroll
    for (int k = 0; k < 16; ++k) { u0[k] *= rstdL[k]; u1[k] *= rstdL[k]; }
    const float al = *alpha_p;
    const float rc0 = rmsw[c0]*al, rc1 = rmsw[c0+1]*al;
    const uint32_t* wrow = (const uint32_t*)wT + tid;   // dword = channels (2t,2t+1)
    float hn0[16], hn1[16];
    #pragma unroll
    for (int p = 0; p < 16; ++p) {
        float a0 = 0.f, a1 = 0.f;
        #pragma unroll
        for (int k = 0; k < 16; ++k) {
            uint32_t wz = wrow[(p*16 + k)*256];
            float w0 = __builtin_bit_cast(float, wz << 16);
            float w1 = __builtin_bit_cast(float, wz & 0xffff0000u);
            a0 += w0*u0[k]; a1 += w1*u1[k];
        }
        hn0[p] = raw[p][c0]   + rc0*a0;
        hn1[p] = raw[p][c0+1] + rc1*a1;
        float2 o; o.x = hn0[p]; o.y = hn1[p];
        *(float2*)&h[(size_t)(base + p*STR)*NH + c0] = o;
    }
    if constexpr (FFN) {
        float p2[16];
        #pragma unroll
        for (int p = 0; p < 16; ++p) p2[p] = hn0[p]*hn0[p] + hn1[p]*hn1[p];
        #pragma unroll
        for (int m = 1; m < 64; m <<= 1)
            #pragma unroll
            for (int p = 0; p < 16; ++p) p2[p] += __shfl_xor(p2[p], m, 64);
        __syncthreads();
        if (lane == 0) {
            #pragma unroll
            for (int p = 0; p < 16; ++p) red[wid][p] = p2[p];
        }
        __syncthreads();
        if (tid < 16)
            rstdL[tid] = rsqrtf((red[0][tid]+red[1][tid]+red[2][tid]+red[3][tid])*(1.f/NH) + EPSF);
        __syncthreads();
        const float rf0 = rmsw_ffn[c0], rf1 = rmsw_ffn[c0+1];
        #pragma unroll
        for (int p = 0; p < 16; ++p) {
            float r = rstdL[p];
            uint32_t pk = ((uint32_t)bfbits(hn1[p]*r*rf1) << 16) | bfbits(hn0[p]*r*rf0);
            *(uint32_t*)&a_bf[(size_t)(base + p*STR)*NH + c0] = pk;
        }
    }
}

// ---------------- head norm: a[t,c] = bf16(h[t,c]*rstd(t)*rmsw[c]) (self-contained)
__global__ __launch_bounds__(256) void k_norm2(
    const float* __restrict__ h, const float* __restrict__ rmsw,
    bf16* __restrict__ a)
{
    const int t = blockIdx.x*4 + (threadIdx.x >> 6);
    const int lane = threadIdx.x & 63;
    const int c8 = lane*8;
    const float* src = &h[(size_t)t*NH + c8];
    float4 h0 = *(const float4*)&src[0];
    float4 h1 = *(const float4*)&src[4];
    float ss = h0.x*h0.x + h0.y*h0.y + h0.z*h0.z + h0.w*h0.w
             + h1.x*h1.x + h1.y*h1.y + h1.z*h1.z + h1.w*h1.w;
    #pragma unroll
    for (int m = 1; m < 64; m <<= 1) ss += __shfl_xor(ss, m, 64);
    const float rstd = rsqrtf(ss*(1.f/NH) + EPSF);
    float4 w0 = *(const float4*)&rmsw[c8];
    float4 w1 = *(const float4*)&rmsw[c8 + 4];
    bf16x8 o;
    o[0] = f2bf(h0.x*rstd*w0.x); o[1] = f2bf(h0.y*rstd*w0.y);
    o[2] = f2bf(h0.z*rstd*w0.z); o[3] = f2bf(h0.w*rstd*w0.w);
    o[4] = f2bf(h1.x*rstd*w1.x); o[5] = f2bf(h1.y*rstd*w1.y);
    o[6] = f2bf(h1.z*rstd*w1.z); o[7] = f2bf(h1.w*rstd*w1.w);
    *(bf16x8*)&a[(size_t)t*NH + c8] = o;
}

// ---------------- mlp in: g = silu(wv . a) * (wg . a)   (bf16 out)
__global__ __launch_bounds__(256) void k_mlp_in(
    const bf16* __restrict__ a, const bf16* __restrict__ wvl,
    const bf16* __restrict__ wgl, bf16* __restrict__ g)
{
    __shared__ __align__(16) bf16 As[2][4096], B1s[2][4096], B3s[2][4096];
    __shared__ bf16 Gs[64*72];
    const int t0 = blockIdx.x*64, n0 = blockIdx.y*64;
    const int tid = threadIdx.x, lane = tid & 63, wv_ = tid >> 6;
    const int wm = wv_ >> 1, wn = wv_ & 1;
    const int fr = lane & 15, kq = lane >> 4;
    const bf16* Ag = a   + (size_t)t0*NH;
    const bf16* Vg = wvl + (size_t)n0*NH;
    const bf16* Gg = wgl + (size_t)n0*NH;
    f32x4 acc1[2][2] = {}, acc3[2][2] = {};
    stage64(Ag, NH, As[0],  wv_, lane);
    stage64(Vg, NH, B1s[0], wv_, lane);
    stage64(Gg, NH, B3s[0], wv_, lane);
    __syncthreads();
    const int NIT = NH/64;
    for (int it = 0; it < NIT; ++it) {
        const int cur = it & 1;
        if (it + 1 < NIT) {
            stage64(Ag + (it+1)*64, NH, As[cur^1],  wv_, lane);
            stage64(Vg + (it+1)*64, NH, B1s[cur^1], wv_, lane);
            stage64(Gg + (it+1)*64, NH, B3s[cur^1], wv_, lane);
        }
        #pragma unroll
        for (int kk = 0; kk < 2; ++kk) {
            const int ch = kk*4 + kq;
            bf16x8 a0 = *fragp(As[cur],  wm*32 + fr,      ch);
            bf16x8 a1 = *fragp(As[cur],  wm*32 + 16 + fr, ch);
            bf16x8 u0 = *fragp(B1s[cur], wn*32 + fr,      ch);
            bf16x8 u1 = *fragp(B1s[cur], wn*32 + 16 + fr, ch);
            bf16x8 v0 = *fragp(B3s[cur], wn*32 + fr,      ch);
            bf16x8 v1 = *fragp(B3s[cur], wn*32 + 16 + fr, ch);
            acc1[0][0] = MFMA(a0, u0, acc1[0][0]);
            acc1[0][1] = MFMA(a0, u1, acc1[0][1]);
            acc1[1][0] = MFMA(a1, u0, acc1[1][0]);
            acc1[1][1] = MFMA(a1, u1, acc1[1][1]);
            acc3[0][0] = MFMA(a0, v0, acc3[0][0]);
            acc3[0][1] = MFMA(a0, v1, acc3[0][1]);
            acc3[1][0] = MFMA(a1, v0, acc3[1][0]);
            acc3[1][1] = MFMA(a1, v1, acc3[1][1]);
        }
        __syncthreads();
    }
    const int row4 = (lane >> 4)*4, col = lane & 15;
    #pragma unroll
    for (int mi = 0; mi < 2; ++mi)
      #pragma unroll
      for (int ni = 0; ni < 2; ++ni)
        #pragma unroll
        for (int r = 0; r < 4; ++r) {
            float xv = acc1[mi][ni][r];
            float gl = (xv / (1.f + __expf(-xv))) * acc3[mi][ni][r];
            Gs[(wm*32 + mi*16 + row4 + r)*72 + wn*32 + ni*16 + col] = f2bf(gl);
        }
    __syncthreads();
    const int rr = tid >> 2, c16 = (tid & 3)*16;
    bf16x8 o0 = *(const bf16x8*)&Gs[rr*72 + c16];
    bf16x8 o1 = *(const bf16x8*)&Gs[rr*72 + c16 + 8];
    *(bf16x8*)&g[(size_t)(t0 + rr)*NG + n0 + c16] = o0;
    *(bf16x8*)&g[(size_t)(t0 + rr)*NG + n0 + c16 + 8] = o1;
}

// ---------------- mlp out: h += alpha * (wo . g)
__global__ __launch_bounds__(256) void k_mlp_out(
    const bf16* __restrict__ g, const bf16* __restrict__ wol,
    const float* __restrict__ alpha_p, float* __restrict__ h)
{
    __shared__ __align__(16) bf16 As[2][4096], Bs[2][4096];
    __shared__ float Cs[64*66];
    const int t0 = blockIdx.x*64, n0 = blockIdx.y*64;
    const int tid = threadIdx.x, lane = tid & 63, wv_ = tid >> 6;
    const int wm = wv_ >> 1, wn = wv_ & 1;
    const int fr = lane & 15, kq = lane >> 4;
    const bf16* Ag = g   + (size_t)t0*NG;
    const bf16* Bg = wol + (size_t)n0*NG;
    f32x4 acc[2][2] = {};
    stage64(Ag, NG, As[0], wv_, lane);
    stage64(Bg, NG, Bs[0], wv_, lane);
    __syncthreads();
    const int NIT = NG/64;
    for (int it = 0; it < NIT; ++it) {
        const int cur = it & 1;
        if (it + 1 < NIT) {
            stage64(Ag + (it+1)*64, NG, As[cur^1], wv_, lane);
            stage64(Bg + (it+1)*64, NG, Bs[cur^1], wv_, lane);
        }
        #pragma unroll
        for (int kk = 0; kk < 2; ++kk) {
            const int ch = kk*4 + kq;
            bf16x8 a0 = *fragp(As[cur], wm*32 + fr,      ch);
            bf16x8 a1 = *fragp(As[cur], wm*32 + 16 + fr, ch);
            bf16x8 b0 = *fragp(Bs[cur], wn*32 + fr,      ch);
            bf16x8 b1 = *fragp(Bs[cur], wn*32 + 16 + fr, ch);
            acc[0][0] = MFMA(a0, b0, acc[0][0]);
            acc[0][1] = MFMA(a0, b1, acc[0][1]);
            acc[1][0] = MFMA(a1, b0, acc[1][0]);
            acc[1][1] = MFMA(a1, b1, acc[1][1]);
        }
        __syncthreads();
    }
    const int row4 = (lane >> 4)*4, col = lane & 15;
    #pragma unroll
    for (int mi = 0; mi < 2; ++mi)
      #pragma unroll
      for (int ni = 0; ni < 2; ++ni)
        #pragma unroll
        for (int r = 0; r < 4; ++r)
            Cs[(wm*32 + mi*16 + row4 + r)*66 + wn*32 + ni*16 + col] = acc[mi][ni][r];
    __syncthreads();
    const float am = *alpha_p;
    const int rr = tid >> 2, c16 = (tid & 3)*16;
    float* dst = &h[(size_t)(t0 + rr)*NH + n0 + c16];
    #pragma unroll
    for (int i = 0; i < 16; ++i)
        dst[i] = dst[i] + am * Cs[rr*66 + c16 + i];
}

// ---------------- head: logits = scale * head_w . a
__global__ __launch_bounds__(256) void k_head(
    const bf16* __restrict__ a, const bf16* __restrict__ hw,
    const float* __restrict__ scale_p, float* __restrict__ out)
{
    __shared__ __align__(16) bf16 As[2][4096], Bs[2][4096];
    __shared__ float Ls[64*66];
    const int t0 = blockIdx.x*64, n0 = blockIdx.y*64;
    const int tid = threadIdx.x, lane = tid & 63, wv_ = tid >> 6;
    const int wm = wv_ >> 1, wn = wv_ & 1;
    const int fr = lane & 15, kq = lane >> 4;
    const bf16* Ag = a  + (size_t)t0*NH;
    const bf16* Bg = hw + (size_t)n0*NH;
    f32x4 acc[2][2] = {};
    stage64(Ag, NH, As[0], wv_, lane);
    stage64(Bg, NH, Bs[0], wv_, lane);
    __syncthreads();
    const int NIT = NH/64;
    for (int it = 0; it < NIT; ++it) {
        const int cur = it & 1;
        if (it + 1 < NIT) {
            stage64(Ag + (it+1)*64, NH, As[cur^1], wv_, lane);
            stage64(Bg + (it+1)*64, NH, Bs[cur^1], wv_, lane);
        }
        #pragma unroll
        for (int kk = 0; kk < 2; ++kk) {
            const int ch = kk*4 + kq;
            bf16x8 a0 = *fragp(As[cur], wm*32 + fr,      ch);
            bf16x8 a1 = *fragp(As[cur], wm*32 + 16 + fr, ch);
            bf16x8 b0 = *fragp(Bs[cur], wn*32 + fr,      ch);
            bf16x8 b1 = *fragp(Bs[cur], wn*32 + 16 + fr, ch);
            acc[0][0] = MFMA(a0, b0, acc[0][0]);
            acc[0][1] = MFMA(a0, b1, acc[0][1]);
            acc[1][0] = MFMA(a1, b0, acc[1][0]);
            acc[1][1] = MFMA(a1, b1, acc[1][1]);
        }
        __syncthreads();
    }
    const float sc = *scale_p;
    const int row4 = (lane >> 4)*4, col = lane & 15;
    #pragma unroll
    for (int mi = 0; mi < 2; ++mi)
      #pragma unroll
      for (int ni = 0; ni < 2; ++ni)
        #pragma unroll
        for (int r = 0; r < 4; ++r)
            Ls[(wm*32 + mi*16 + row4 + r)*66 + wn*32 + ni*16 + col] = sc * acc[mi][ni][r];
    __syncthreads();
    const int vv = tid >> 2, s16 = (tid & 3)*16;
    const int b = t0 >> 8, s0 = t0 & 255;
    float* dst = &out[((size_t)(b*NV + n0 + vv))*NS + s0 + s16];
    #pragma unroll
    for (int i = 0; i < 16; ++i) dst[i] = Ls[(s16 + i)*66 + vv];
}

extern "C" void kernel_launch(void* const* d_in, const int* in_sizes, int n_in,
                              void* d_out, int out_size, void* d_ws, size_t ws_size,
                              hipStream_t stream) {
    const float* x          = (const float*)d_in[0];
    const float* stem_w     = (const float*)d_in[1];
    const float* rms_local  = (const float*)d_in[2];
    const float* rms_global = (const float*)d_in[3];
    const float* rms_ffn    = (const float*)d_in[4];
    const float* alpha_local  = (const float*)d_in[5];
    const float* alpha_global = (const float*)d_in[6];
    const float* alpha_mlp    = (const float*)d_in[7];
    const float* w_local    = (const float*)d_in[8];
    const float* w_global   = (const float*)d_in[9];
    const float* wv         = (const float*)d_in[10];
    const float* wg         = (const float*)d_in[11];
    const float* wo         = (const float*)d_in[12];
    const float* head_rms   = (const float*)d_in[13];
    const float* head_scale = (const float*)d_in[14];
    const float* head_w     = (const float*)d_in[15];
    float* out = (float*)d_out;

    char* ws = (char*)d_ws;
    const size_t MB = 1024*1024;
    float* h    = (float*)(ws);                 // 4MB
    bf16*  g    = (bf16*)(ws + 4*MB);           // 4MB
    bf16*  a_bf = (bf16*)(ws + 8*MB);           // 2MB
    bf16* xT      = (bf16*)(ws + 16*MB);        // 1.31MB
    bf16* stem_wb = (bf16*)(ws + 18*MB);        // 0.33MB
    bf16* head_wb = (bf16*)(ws + 19*MB);        // 0.26MB
    bf16* wlT     = (bf16*)(ws + 20*MB);        // 6MB
    bf16* wgT     = (bf16*)(ws + 26*MB);        // 6MB
    bf16* wv_b    = (bf16*)(ws + 32*MB);        // 24MB
    bf16* wg_b    = (bf16*)(ws + 56*MB);        // 24MB
    bf16* wo_b    = (bf16*)(ws + 80*MB);        // 24MB -> end 104MB

    // init: 4 dispatches
    k_cvt3<<<2048, 256, 0, stream>>>(wv, wg, wo, wv_b, wg_b, wo_b, NL*NG*NH/8);
    k_cvt2<<<160, 256, 0, stream>>>(stem_w, head_w, stem_wb, head_wb,
                                    NH*NC/8, NV*NH/8);
    k_trw<<<dim3(4, 8, 48), 256, 0, stream>>>(w_local, w_global, wlT, wgT);
    k_trx<<<dim3(4, 5, 8), 256, 0, stream>>>(x, xT);

    k_stem_b<<<dim3(32, 8), 256, 0, stream>>>(xT, stem_wb, h);

    for (int l = 0; l < NL; ++l) {
        k_mix2<1, false><<<dim3(NB, 16), 256, 0, stream>>>(
            h, wlT + (size_t)l*256*NH, rms_local + l*NH, alpha_local + l,
            nullptr, nullptr);
        k_mix2<16, true><<<dim3(NB, 16), 256, 0, stream>>>(
            h, wgT + (size_t)l*256*NH, rms_global + l*NH, alpha_global + l,
            rms_ffn + l*NH, a_bf);
        k_mlp_in<<<dim3(32, 16), 256, 0, stream>>>(
            a_bf, wv_b + (size_t)l*NG*NH, wg_b + (size_t)l*NG*NH, g);
        k_mlp_out<<<dim3(32, 8), 256, 0, stream>>>(
            g, wo_b + (size_t)l*NH*NG, alpha_mlp + l, h);
    }
    k_norm2<<<512, 256, 0, stream>>>(h, head_rms, a_bf);
    k_head<<<dim3(32, 4), 256, 0, stream>>>(a_bf, head_wb, head_scale, out);
}

// Round 10
// 1235.061 us; speedup vs baseline: 4.2286x; 1.1142x over previous
//
#include <hip/hip_runtime.h>
#include <hip/hip_bf16.h>
#include <stdint.h>

#define NB 8
#define NS 256
#define NH 512
#define NG 1024
#define NV 256
#define NL 24
#define NC 320
#define NT 2048
#define EPSF 1e-5f

typedef __bf16 bf16;
typedef bf16 bf16x8 __attribute__((ext_vector_type(8)));
typedef float f32x4 __attribute__((ext_vector_type(4)));

__device__ __forceinline__ bf16 f2bf(float f) {
    uint32_t u = __builtin_bit_cast(uint32_t, f);
    u += 0x7FFFu + ((u >> 16) & 1u);
    uint16_t b = (uint16_t)(u >> 16);
    return __builtin_bit_cast(bf16, b);
}
__device__ __forceinline__ uint16_t bfbits(float f) {
    uint32_t u = __builtin_bit_cast(uint32_t, f);
    u += 0x7FFFu + ((u >> 16) & 1u);
    return (uint16_t)(u >> 16);
}

__device__ __forceinline__ void gload16(const void* g, void* l) {
    __builtin_amdgcn_global_load_lds(
        (const __attribute__((address_space(1))) void*)g,
        (__attribute__((address_space(3))) void*)l,
        16, 0, 0);
}

// stage 64-row x 64-elem bf16 tile; LDS chunk XOR-swizzled via pre-swizzled src
__device__ __forceinline__ void stage64(
    const bf16* __restrict__ src, int ldk, bf16* lds, int wv_, int lane)
{
    #pragma unroll
    for (int j = 0; j < 2; ++j) {
        const int gI = wv_*2 + j;
        const int r  = gI*8 + (lane >> 3);
        const int ch = (lane & 7) ^ (lane >> 3);
        gload16(src + (size_t)r*ldk + ch*8, lds + gI*512);
    }
}
__device__ __forceinline__ const bf16x8* fragp(const bf16* lds, int row, int ch) {
    return (const bf16x8*)(lds + row*64 + ((ch ^ (row & 7)) << 3));
}

#define MFMA(a,b,c) __builtin_amdgcn_mfma_f32_16x16x32_bf16(a, b, c, 0, 0, 0)

// ---------------- init: f32 -> bf16 bulk convert (n8 = elems/8)
__global__ __launch_bounds__(256) void k_cvt(
    const float* __restrict__ src, bf16* __restrict__ dst, int n8)
{
    int i = blockIdx.x*256 + threadIdx.x;
    const int stride = gridDim.x*256;
    for (; i < n8; i += stride) {
        const float* sp = src + (size_t)i*8;
        float4 v0 = *(const float4*)&sp[0];
        float4 v1 = *(const float4*)&sp[4];
        bf16x8 t;
        t[0] = f2bf(v0.x); t[1] = f2bf(v0.y); t[2] = f2bf(v0.z); t[3] = f2bf(v0.w);
        t[4] = f2bf(v1.x); t[5] = f2bf(v1.y); t[6] = f2bf(v1.z); t[7] = f2bf(v1.w);
        *(bf16x8*)&dst[(size_t)i*8] = t;
    }
}

// ---------------- init: stem + head weights
__global__ __launch_bounds__(256) void k_cvt2(
    const float* __restrict__ s0, const float* __restrict__ s1,
    bf16* __restrict__ d0, bf16* __restrict__ d1, int n8a, int n8b)
{
    const int N = n8a + n8b;
    for (int i = blockIdx.x*256 + threadIdx.x; i < N; i += gridDim.x*256) {
        const float* s; bf16* d; int j;
        if (i < n8a) { s = s0; d = d0; j = i; }
        else         { s = s1; d = d1; j = i - n8a; }
        const float* sp = s + (size_t)j*8;
        float4 v0 = *(const float4*)&sp[0];
        float4 v1 = *(const float4*)&sp[4];
        bf16x8 t;
        t[0] = f2bf(v0.x); t[1] = f2bf(v0.y); t[2] = f2bf(v0.z); t[3] = f2bf(v0.w);
        t[4] = f2bf(v1.x); t[5] = f2bf(v1.y); t[6] = f2bf(v1.z); t[7] = f2bf(v1.w);
        *(bf16x8*)&d[(size_t)j*8] = t;
    }
}

// ---------------- init: transpose mix weights [l][c][pj] f32 -> [l][pj][c] bf16
__global__ __launch_bounds__(256) void k_trw(
    const float* __restrict__ wl, const float* __restrict__ wg,
    bf16* __restrict__ wlT, bf16* __restrict__ wgT)
{
    __shared__ bf16 Ls[64*72];
    const int pj0 = blockIdx.x*64, c0 = blockIdx.y*64;
    const int z = blockIdx.z, l = z >> 1;
    const float* src = (z & 1) ? wg : wl;
    bf16* dst = (z & 1) ? wgT : wlT;
    src += (size_t)l*NH*256;
    dst += (size_t)l*256*NH;
    const int tid = threadIdx.x;
    #pragma unroll
    for (int e = 0; e < 16; ++e) {
        int idx = e*256 + tid;
        int cl = idx >> 6, pj = idx & 63;
        Ls[pj*72 + cl] = f2bf(src[(size_t)(c0 + cl)*256 + pj0 + pj]);
    }
    __syncthreads();
    #pragma unroll
    for (int e = 0; e < 2; ++e) {
        int idx = e*256 + tid;
        int row = idx >> 3, ch8 = idx & 7;
        *(bf16x8*)&dst[(size_t)(pj0 + row)*NH + c0 + ch8*8] =
            *(const bf16x8*)&Ls[row*72 + ch8*8];
    }
}

// ---------------- init: x[b][c][s] f32 -> xT[b*256+s][c] bf16
__global__ __launch_bounds__(256) void k_trx(
    const float* __restrict__ x, bf16* __restrict__ xT)
{
    __shared__ bf16 Ls[64*72];
    const int s0 = blockIdx.x*64, c0 = blockIdx.y*64, b = blockIdx.z;
    const int tid = threadIdx.x;
    #pragma unroll
    for (int e = 0; e < 16; ++e) {
        int idx = tid + e*256;
        int c = idx >> 6, s = idx & 63;
        Ls[s*72 + c] = f2bf(x[(size_t)(b*NC + c0 + c)*NS + s0 + s]);
    }
    __syncthreads();
    #pragma unroll
    for (int e = 0; e < 2; ++e) {
        int idx = tid + e*256;
        int s = idx >> 3, ch = idx & 7;
        *(bf16x8*)&xT[(size_t)(b*NS + s0 + s)*NC + c0 + ch*8] =
            *(const bf16x8*)&Ls[s*72 + ch*8];
    }
}

// ---------------- stem GEMM: h[t,o] = xT[t,:] . wb[o,:]
__global__ __launch_bounds__(256) void k_stem_b(
    const bf16* __restrict__ xT, const bf16* __restrict__ wb,
    float* __restrict__ h)
{
    __shared__ __align__(16) bf16 As[2][4096], Bs[2][4096];
    __shared__ float Cs[64*66];
    const int t0 = blockIdx.x*64, n0 = blockIdx.y*64;
    const int tid = threadIdx.x, lane = tid & 63, wv_ = tid >> 6;
    const int wm = wv_ >> 1, wn = wv_ & 1;
    const int fr = lane & 15, kq = lane >> 4;
    const bf16* Ag = xT + (size_t)t0*NC;
    const bf16* Bg = wb + (size_t)n0*NC;
    f32x4 acc[2][2] = {};
    stage64(Ag, NC, As[0], wv_, lane);
    stage64(Bg, NC, Bs[0], wv_, lane);
    __syncthreads();
    const int NIT = NC/64;
    for (int it = 0; it < NIT; ++it) {
        const int cur = it & 1;
        if (it + 1 < NIT) {
            stage64(Ag + (it+1)*64, NC, As[cur^1], wv_, lane);
            stage64(Bg + (it+1)*64, NC, Bs[cur^1], wv_, lane);
        }
        #pragma unroll
        for (int kk = 0; kk < 2; ++kk) {
            const int ch = kk*4 + kq;
            bf16x8 a0 = *fragp(As[cur], wm*32 + fr,      ch);
            bf16x8 a1 = *fragp(As[cur], wm*32 + 16 + fr, ch);
            bf16x8 b0 = *fragp(Bs[cur], wn*32 + fr,      ch);
            bf16x8 b1 = *fragp(Bs[cur], wn*32 + 16 + fr, ch);
            acc[0][0] = MFMA(a0, b0, acc[0][0]);
            acc[0][1] = MFMA(a0, b1, acc[0][1]);
            acc[1][0] = MFMA(a1, b0, acc[1][0]);
            acc[1][1] = MFMA(a1, b1, acc[1][1]);
        }
        __syncthreads();
    }
    const int row4 = (lane >> 4)*4, col = lane & 15;
    #pragma unroll
    for (int mi = 0; mi < 2; ++mi)
      #pragma unroll
      for (int ni = 0; ni < 2; ++ni)
        #pragma unroll
        for (int r = 0; r < 4; ++r)
            Cs[(wm*32 + mi*16 + row4 + r)*66 + wn*32 + ni*16 + col] = acc[mi][ni][r];
    __syncthreads();
    const int rr = tid >> 2, c16 = (tid & 3)*16;
    float* dst = &h[(size_t)(t0 + rr)*NH + n0 + c16];
    #pragma unroll
    for (int i = 0; i < 16; ++i) dst[i] = Cs[rr*66 + c16 + i];
}

// ---------------- unified mix with block-local RMS norm, split output-tokens
// STR=1 (local): tokens base+k, base = b*256 + gi*16
// STR=16(global): tokens base+16k, base = b*256 + gi
// blockIdx.z = ph picks output tokens p = ph*8 .. ph*8+7 (inputs k = all 16)
// FFN: additionally compute ffn-norm of updated rows and write a_bf
template<int STR, bool FFN>
__global__ __launch_bounds__(256) void k_mix2(
    float* __restrict__ h, const bf16* __restrict__ wT,
    const float* __restrict__ rmsw, const float* __restrict__ alpha_p,
    const float* __restrict__ rmsw_ffn, bf16* __restrict__ a_bf)
{
    __shared__ float raw[16][512];
    __shared__ float red[4][16];
    __shared__ float rstdL[16];
    const int b = blockIdx.x, gi = blockIdx.y, ph = blockIdx.z;
    const int base = b*NS + (STR == 1 ? gi*16 : gi);
    const int tid = threadIdx.x, lane = tid & 63, wid = tid >> 6;
    #pragma unroll
    for (int e = 0; e < 8; ++e) {
        int idx = e*256 + tid;
        int k = idx >> 7, c4 = idx & 127;
        *(float4*)&raw[k][c4*4] = *(const float4*)&h[(size_t)(base + k*STR)*NH + c4*4];
    }
    __syncthreads();
    const int c0 = tid*2;
    float u0[16], u1[16], part[16];
    #pragma unroll
    for (int k = 0; k < 16; ++k) {
        float A = raw[k][c0], B = raw[k][c0+1];
        u0[k] = A; u1[k] = B; part[k] = A*A + B*B;
    }
    #pragma unroll
    for (int m = 1; m < 64; m <<= 1)
        #pragma unroll
        for (int k = 0; k < 16; ++k) part[k] += __shfl_xor(part[k], m, 64);
    if (lane == 0) {
        #pragma unroll
        for (int k = 0; k < 16; ++k) red[wid][k] = part[k];
    }
    __syncthreads();
    if (tid < 16)
        rstdL[tid] = rsqrtf((red[0][tid]+red[1][tid]+red[2][tid]+red[3][tid])*(1.f/NH) + EPSF);
    __syncthreads();
    #pragma unroll
    for (int k = 0; k < 16; ++k) { u0[k] *= rstdL[k]; u1[k] *= rstdL[k]; }
    const float al = *alpha_p;
    const float rc0 = rmsw[c0]*al, rc1 = rmsw[c0+1]*al;
    const uint32_t* wrow = (const uint32_t*)wT + tid;   // dword = channels (2t,2t+1)
    float hn0[8], hn1[8];
    #pragma unroll
    for (int pp = 0; pp < 8; ++pp) {
        const int p = ph*8 + pp;
        float a0 = 0.f, a1 = 0.f;
        #pragma unroll
        for (int k = 0; k < 16; ++k) {
            uint32_t wz = wrow[(p*16 + k)*256];
            float w0 = __builtin_bit_cast(float, wz << 16);
            float w1 = __builtin_bit_cast(float, wz & 0xffff0000u);
            a0 += w0*u0[k]; a1 += w1*u1[k];
        }
        hn0[pp] = raw[p][c0]   + rc0*a0;
        hn1[pp] = raw[p][c0+1] + rc1*a1;
        float2 o; o.x = hn0[pp]; o.y = hn1[pp];
        *(float2*)&h[(size_t)(base + p*STR)*NH + c0] = o;
    }
    if constexpr (FFN) {
        float p2[8];
        #pragma unroll
        for (int pp = 0; pp < 8; ++pp) p2[pp] = hn0[pp]*hn0[pp] + hn1[pp]*hn1[pp];
        #pragma unroll
        for (int m = 1; m < 64; m <<= 1)
            #pragma unroll
            for (int pp = 0; pp < 8; ++pp) p2[pp] += __shfl_xor(p2[pp], m, 64);
        __syncthreads();
        if (lane == 0) {
            #pragma unroll
            for (int pp = 0; pp < 8; ++pp) red[wid][pp] = p2[pp];
        }
        __syncthreads();
        if (tid < 8)
            rstdL[tid] = rsqrtf((red[0][tid]+red[1][tid]+red[2][tid]+red[3][tid])*(1.f/NH) + EPSF);
        __syncthreads();
        const float rf0 = rmsw_ffn[c0], rf1 = rmsw_ffn[c0+1];
        #pragma unroll
        for (int pp = 0; pp < 8; ++pp) {
            const int p = ph*8 + pp;
            float r = rstdL[pp];
            uint32_t pk = ((uint32_t)bfbits(hn1[pp]*r*rf1) << 16) | bfbits(hn0[pp]*r*rf0);
            *(uint32_t*)&a_bf[(size_t)(base + p*STR)*NH + c0] = pk;
        }
    }
}

// ---------------- head norm: a[t,c] = bf16(h[t,c]*rstd(t)*rmsw[c])
__global__ __launch_bounds__(256) void k_norm2(
    const float* __restrict__ h, const float* __restrict__ rmsw,
    bf16* __restrict__ a)
{
    const int t = blockIdx.x*4 + (threadIdx.x >> 6);
    const int lane = threadIdx.x & 63;
    const int c8 = lane*8;
    const float* src = &h[(size_t)t*NH + c8];
    float4 h0 = *(const float4*)&src[0];
    float4 h1 = *(const float4*)&src[4];
    float ss = h0.x*h0.x + h0.y*h0.y + h0.z*h0.z + h0.w*h0.w
             + h1.x*h1.x + h1.y*h1.y + h1.z*h1.z + h1.w*h1.w;
    #pragma unroll
    for (int m = 1; m < 64; m <<= 1) ss += __shfl_xor(ss, m, 64);
    const float rstd = rsqrtf(ss*(1.f/NH) + EPSF);
    float4 w0 = *(const float4*)&rmsw[c8];
    float4 w1 = *(const float4*)&rmsw[c8 + 4];
    bf16x8 o;
    o[0] = f2bf(h0.x*rstd*w0.x); o[1] = f2bf(h0.y*rstd*w0.y);
    o[2] = f2bf(h0.z*rstd*w0.z); o[3] = f2bf(h0.w*rstd*w0.w);
    o[4] = f2bf(h1.x*rstd*w1.x); o[5] = f2bf(h1.y*rstd*w1.y);
    o[6] = f2bf(h1.z*rstd*w1.z); o[7] = f2bf(h1.w*rstd*w1.w);
    *(bf16x8*)&a[(size_t)t*NH + c8] = o;
}

// ---------------- mlp in: g = silu(wv . a) * (wg . a)   (bf16 out)
__global__ __launch_bounds__(256) void k_mlp_in(
    const bf16* __restrict__ a, const bf16* __restrict__ wvl,
    const bf16* __restrict__ wgl, bf16* __restrict__ g)
{
    __shared__ __align__(16) bf16 As[2][4096], B1s[2][4096], B3s[2][4096];
    __shared__ bf16 Gs[64*72];
    const int t0 = blockIdx.x*64, n0 = blockIdx.y*64;
    const int tid = threadIdx.x, lane = tid & 63, wv_ = tid >> 6;
    const int wm = wv_ >> 1, wn = wv_ & 1;
    const int fr = lane & 15, kq = lane >> 4;
    const bf16* Ag = a   + (size_t)t0*NH;
    const bf16* Vg = wvl + (size_t)n0*NH;
    const bf16* Gg = wgl + (size_t)n0*NH;
    f32x4 acc1[2][2] = {}, acc3[2][2] = {};
    stage64(Ag, NH, As[0],  wv_, lane);
    stage64(Vg, NH, B1s[0], wv_, lane);
    stage64(Gg, NH, B3s[0], wv_, lane);
    __syncthreads();
    const int NIT = NH/64;
    for (int it = 0; it < NIT; ++it) {
        const int cur = it & 1;
        if (it + 1 < NIT) {
            stage64(Ag + (it+1)*64, NH, As[cur^1],  wv_, lane);
            stage64(Vg + (it+1)*64, NH, B1s[cur^1], wv_, lane);
            stage64(Gg + (it+1)*64, NH, B3s[cur^1], wv_, lane);
        }
        #pragma unroll
        for (int kk = 0; kk < 2; ++kk) {
            const int ch = kk*4 + kq;
            bf16x8 a0 = *fragp(As[cur],  wm*32 + fr,      ch);
            bf16x8 a1 = *fragp(As[cur],  wm*32 + 16 + fr, ch);
            bf16x8 u0 = *fragp(B1s[cur], wn*32 + fr,      ch);
            bf16x8 u1 = *fragp(B1s[cur], wn*32 + 16 + fr, ch);
            bf16x8 v0 = *fragp(B3s[cur], wn*32 + fr,      ch);
            bf16x8 v1 = *fragp(B3s[cur], wn*32 + 16 + fr, ch);
            acc1[0][0] = MFMA(a0, u0, acc1[0][0]);
            acc1[0][1] = MFMA(a0, u1, acc1[0][1]);
            acc1[1][0] = MFMA(a1, u0, acc1[1][0]);
            acc1[1][1] = MFMA(a1, u1, acc1[1][1]);
            acc3[0][0] = MFMA(a0, v0, acc3[0][0]);
            acc3[0][1] = MFMA(a0, v1, acc3[0][1]);
            acc3[1][0] = MFMA(a1, v0, acc3[1][0]);
            acc3[1][1] = MFMA(a1, v1, acc3[1][1]);
        }
        __syncthreads();
    }
    const int row4 = (lane >> 4)*4, col = lane & 15;
    #pragma unroll
    for (int mi = 0; mi < 2; ++mi)
      #pragma unroll
      for (int ni = 0; ni < 2; ++ni)
        #pragma unroll
        for (int r = 0; r < 4; ++r) {
            float xv = acc1[mi][ni][r];
            float gl = (xv / (1.f + __expf(-xv))) * acc3[mi][ni][r];
            Gs[(wm*32 + mi*16 + row4 + r)*72 + wn*32 + ni*16 + col] = f2bf(gl);
        }
    __syncthreads();
    const int rr = tid >> 2, c16 = (tid & 3)*16;
    bf16x8 o0 = *(const bf16x8*)&Gs[rr*72 + c16];
    bf16x8 o1 = *(const bf16x8*)&Gs[rr*72 + c16 + 8];
    *(bf16x8*)&g[(size_t)(t0 + rr)*NG + n0 + c16] = o0;
    *(bf16x8*)&g[(size_t)(t0 + rr)*NG + n0 + c16 + 8] = o1;
}

// ---------------- mlp out: h += alpha * (wo . g)
__global__ __launch_bounds__(256) void k_mlp_out(
    const bf16* __restrict__ g, const bf16* __restrict__ wol,
    const float* __restrict__ alpha_p, float* __restrict__ h)
{
    __shared__ __align__(16) bf16 As[2][4096], Bs[2][4096];
    __shared__ float Cs[64*66];
    const int t0 = blockIdx.x*64, n0 = blockIdx.y*64;
    const int tid = threadIdx.x, lane = tid & 63, wv_ = tid >> 6;
    const int wm = wv_ >> 1, wn = wv_ & 1;
    const int fr = lane & 15, kq = lane >> 4;
    const bf16* Ag = g   + (size_t)t0*NG;
    const bf16* Bg = wol + (size_t)n0*NG;
    f32x4 acc[2][2] = {};
    stage64(Ag, NG, As[0], wv_, lane);
    stage64(Bg, NG, Bs[0], wv_, lane);
    __syncthreads();
    const int NIT = NG/64;
    for (int it = 0; it < NIT; ++it) {
        const int cur = it & 1;
        if (it + 1 < NIT) {
            stage64(Ag + (it+1)*64, NG, As[cur^1], wv_, lane);
            stage64(Bg + (it+1)*64, NG, Bs[cur^1], wv_, lane);
        }
        #pragma unroll
        for (int kk = 0; kk < 2; ++kk) {
            const int ch = kk*4 + kq;
            bf16x8 a0 = *fragp(As[cur], wm*32 + fr,      ch);
            bf16x8 a1 = *fragp(As[cur], wm*32 + 16 + fr, ch);
            bf16x8 b0 = *fragp(Bs[cur], wn*32 + fr,      ch);
            bf16x8 b1 = *fragp(Bs[cur], wn*32 + 16 + fr, ch);
            acc[0][0] = MFMA(a0, b0, acc[0][0]);
            acc[0][1] = MFMA(a0, b1, acc[0][1]);
            acc[1][0] = MFMA(a1, b0, acc[1][0]);
            acc[1][1] = MFMA(a1, b1, acc[1][1]);
        }
        __syncthreads();
    }
    const int row4 = (lane >> 4)*4, col = lane & 15;
    #pragma unroll
    for (int mi = 0; mi < 2; ++mi)
      #pragma unroll
      for (int ni = 0; ni < 2; ++ni)
        #pragma unroll
        for (int r = 0; r < 4; ++r)
            Cs[(wm*32 + mi*16 + row4 + r)*66 + wn*32 + ni*16 + col] = acc[mi][ni][r];
    __syncthreads();
    const float am = *alpha_p;
    const int rr = tid >> 2, c16 = (tid & 3)*16;
    float* dst = &h[(size_t)(t0 + rr)*NH + n0 + c16];
    #pragma unroll
    for (int i = 0; i < 16; ++i)
        dst[i] = dst[i] + am * Cs[rr*66 + c16 + i];
}

// ---------------- head: logits = scale * head_w . a
__global__ __launch_bounds__(256) void k_head(
    const bf16* __restrict__ a, const bf16* __restrict__ hw,
    const float* __restrict__ scale_p, float* __restrict__ out)
{
    __shared__ __align__(16) bf16 As[2][4096], Bs[2][4096];
    __shared__ float Ls[64*66];
    const int t0 = blockIdx.x*64, n0 = blockIdx.y*64;
    const int tid = threadIdx.x, lane = tid & 63, wv_ = tid >> 6;
    const int wm = wv_ >> 1, wn = wv_ & 1;
    const int fr = lane & 15, kq = lane >> 4;
    const bf16* Ag = a  + (size_t)t0*NH;
    const bf16* Bg = hw + (size_t)n0*NH;
    f32x4 acc[2][2] = {};
    stage64(Ag, NH, As[0], wv_, lane);
    stage64(Bg, NH, Bs[0], wv_, lane);
    __syncthreads();
    const int NIT = NH/64;
    for (int it = 0; it < NIT; ++it) {
        const int cur = it & 1;
        if (it + 1 < NIT) {
            stage64(Ag + (it+1)*64, NH, As[cur^1], wv_, lane);
            stage64(Bg + (it+1)*64, NH, Bs[cur^1], wv_, lane);
        }
        #pragma unroll
        for (int kk = 0; kk < 2; ++kk) {
            const int ch = kk*4 + kq;
            bf16x8 a0 = *fragp(As[cur], wm*32 + fr,      ch);
            bf16x8 a1 = *fragp(As[cur], wm*32 + 16 + fr, ch);
            bf16x8 b0 = *fragp(Bs[cur], wn*32 + fr,      ch);
            bf16x8 b1 = *fragp(Bs[cur], wn*32 + 16 + fr, ch);
            acc[0][0] = MFMA(a0, b0, acc[0][0]);
            acc[0][1] = MFMA(a0, b1, acc[0][1]);
            acc[1][0] = MFMA(a1, b0, acc[1][0]);
            acc[1][1] = MFMA(a1, b1, acc[1][1]);
        }
        __syncthreads();
    }
    const float sc = *scale_p;
    const int row4 = (lane >> 4)*4, col = lane & 15;
    #pragma unroll
    for (int mi = 0; mi < 2; ++mi)
      #pragma unroll
      for (int ni = 0; ni < 2; ++ni)
        #pragma unroll
        for (int r = 0; r < 4; ++r)
            Ls[(wm*32 + mi*16 + row4 + r)*66 + wn*32 + ni*16 + col] = sc * acc[mi][ni][r];
    __syncthreads();
    const int vv = tid >> 2, s16 = (tid & 3)*16;
    const int b = t0 >> 8, s0 = t0 & 255;
    float* dst = &out[((size_t)(b*NV + n0 + vv))*NS + s0 + s16];
    #pragma unroll
    for (int i = 0; i < 16; ++i) dst[i] = Ls[(s16 + i)*66 + vv];
}

extern "C" void kernel_launch(void* const* d_in, const int* in_sizes, int n_in,
                              void* d_out, int out_size, void* d_ws, size_t ws_size,
                              hipStream_t stream) {
    const float* x          = (const float*)d_in[0];
    const float* stem_w     = (const float*)d_in[1];
    const float* rms_local  = (const float*)d_in[2];
    const float* rms_global = (const float*)d_in[3];
    const float* rms_ffn    = (const float*)d_in[4];
    const float* alpha_local  = (const float*)d_in[5];
    const float* alpha_global = (const float*)d_in[6];
    const float* alpha_mlp    = (const float*)d_in[7];
    const float* w_local    = (const float*)d_in[8];
    const float* w_global   = (const float*)d_in[9];
    const float* wv         = (const float*)d_in[10];
    const float* wg         = (const float*)d_in[11];
    const float* wo         = (const float*)d_in[12];
    const float* head_rms   = (const float*)d_in[13];
    const float* head_scale = (const float*)d_in[14];
    const float* head_w     = (const float*)d_in[15];
    float* out = (float*)d_out;

    char* ws = (char*)d_ws;
    const size_t MB = 1024*1024;
    float* h    = (float*)(ws);                 // 4MB
    bf16*  g    = (bf16*)(ws + 4*MB);           // 4MB
    bf16*  a_bf = (bf16*)(ws + 8*MB);           // 2MB
    bf16* xT      = (bf16*)(ws + 16*MB);        // 1.31MB
    bf16* stem_wb = (bf16*)(ws + 18*MB);        // 0.33MB
    bf16* head_wb = (bf16*)(ws + 19*MB);        // 0.26MB
    bf16* wlT     = (bf16*)(ws + 20*MB);        // 6MB
    bf16* wgT     = (bf16*)(ws + 26*MB);        // 6MB
    bf16* wv_b    = (bf16*)(ws + 32*MB);        // 24MB
    bf16* wg_b    = (bf16*)(ws + 56*MB);        // 24MB
    bf16* wo_b    = (bf16*)(ws + 80*MB);        // 24MB -> end 104MB

    // init: 6 dispatches (cvt split for diagnosability + BW)
    k_cvt<<<2048, 256, 0, stream>>>(wv, wv_b, NL*NG*NH/8);
    k_cvt<<<2048, 256, 0, stream>>>(wg, wg_b, NL*NG*NH/8);
    k_cvt<<<2048, 256, 0, stream>>>(wo, wo_b, NL*NH*NG/8);
    k_cvt2<<<160, 256, 0, stream>>>(stem_w, head_w, stem_wb, head_wb,
                                    NH*NC/8, NV*NH/8);
    k_trw<<<dim3(4, 8, 48), 256, 0, stream>>>(w_local, w_global, wlT, wgT);
    k_trx<<<dim3(4, 5, 8), 256, 0, stream>>>(x, xT);

    k_stem_b<<<dim3(32, 8), 256, 0, stream>>>(xT, stem_wb, h);

    for (int l = 0; l < NL; ++l) {
        k_mix2<1, false><<<dim3(NB, 16, 2), 256, 0, stream>>>(
            h, wlT + (size_t)l*256*NH, rms_local + l*NH, alpha_local + l,
            nullptr, nullptr);
        k_mix2<16, true><<<dim3(NB, 16, 2), 256, 0, stream>>>(
            h, wgT + (size_t)l*256*NH, rms_global + l*NH, alpha_global + l,
            rms_ffn + l*NH, a_bf);
        k_mlp_in<<<dim3(32, 16), 256, 0, stream>>>(
            a_bf, wv_b + (size_t)l*NG*NH, wg_b + (size_t)l*NG*NH, g);
        k_mlp_out<<<dim3(32, 8), 256, 0, stream>>>(
            g, wo_b + (size_t)l*NH*NG, alpha_mlp + l, h);
    }
    k_norm2<<<512, 256, 0, stream>>>(h, head_rms, a_bf);
    k_head<<<dim3(32, 4), 256, 0, stream>>>(a_bf, head_wb, head_scale, out);
}